// Round 1
// baseline (436.839 us; speedup 1.0000x reference)
//
#include <hip/hip_runtime.h>

// Causal attention head: B=4, T=2048, C=1024, fp32 in/out.
//   k = x@Wk^T, q = x@Wq^T, v = x@Wv^T ; S = q@k^T (no scale, causal) ;
//   P = softmax(S) ; out = P@v
//
// Numerics plan: split-bf16 (hi+lo) 3-pass MFMA for everything feeding the
// softmax logits (x, W, q, k, S) and for v/vT; P is single bf16 (error
// contribution ~1e-3 on out). Expected absmax vs fp32 reference ~1e-3.
//
// Workspace layout (byte offsets; lifetime overlays; total 167,772,160 B = 160 MiB):
//   [0,        67108864)  S fp32 [4][2048][2048]   (written AFTER W+x are dead)
//     [0,      12582912)   W splits: wkhi,wklo,wqhi,wqlo,wvhi,wvlo (2 MiB each)
//     [12582912,46137344)  xhi, xlo (16 MiB each)
//   [67108864, 134217728) qhi,qlo,khi,klo (16 MiB each)
//     [67108864,100663296) P bf16 [4][2048][2048]  (overlays q after S-GEMM done)
//   [134217728,167772160) vthi, vtlo  [4][1024][2048] (16 MiB each)

#define GLOBAL_AS __attribute__((address_space(1)))
#define LDS_AS    __attribute__((address_space(3)))

typedef __attribute__((ext_vector_type(8))) short short8;
typedef __attribute__((ext_vector_type(4))) float f32x4;

__device__ __forceinline__ unsigned short f2bf(float f) {
  unsigned u = __float_as_uint(f);
  u += 0x7FFFu + ((u >> 16) & 1u);   // RTNE (finite values only here)
  return (unsigned short)(u >> 16);
}
__device__ __forceinline__ float bf2f(unsigned short s) {
  return __uint_as_float((unsigned)s << 16);
}

__device__ __forceinline__ void gload_lds16(const unsigned short* g, unsigned short* l) {
  __builtin_amdgcn_global_load_lds((const GLOBAL_AS unsigned int*)g,
                                   (LDS_AS unsigned int*)l, 16, 0, 0);
}

// ---------------- fp32 -> (bf16 hi, bf16 lo) split conversion -----------------
__global__ __launch_bounds__(256) void split_f32_kernel(
    const float* __restrict__ src, unsigned short* __restrict__ hi,
    unsigned short* __restrict__ lo, int n8) {
  int i = blockIdx.x * 256 + threadIdx.x;
  if (i >= n8) return;
  const float4* s4 = (const float4*)src;
  float4 a = s4[2 * i], c = s4[2 * i + 1];
  float v[8] = {a.x, a.y, a.z, a.w, c.x, c.y, c.z, c.w};
  unsigned hw[4], lw[4];
#pragma unroll
  for (int j = 0; j < 4; ++j) {
    unsigned short h0 = f2bf(v[2 * j]),     h1 = f2bf(v[2 * j + 1]);
    unsigned short l0 = f2bf(v[2 * j] - bf2f(h0));
    unsigned short l1 = f2bf(v[2 * j + 1] - bf2f(h1));
    hw[j] = (unsigned)h0 | ((unsigned)h1 << 16);
    lw[j] = (unsigned)l0 | ((unsigned)l1 << 16);
  }
  *(uint4*)(hi + 8 * i) = make_uint4(hw[0], hw[1], hw[2], hw[3]);
  *(uint4*)(lo + 8 * i) = make_uint4(lw[0], lw[1], lw[2], lw[3]);
}

// ---------------- generic 128x128-tile A·B^T GEMM, split-bf16 capable ----------
// A[M][K] (lda=K-stride), B[N][K] (ldb) — both K-contiguous. 256 thr = 4 waves,
// wave tile 64x64 = 4x4 frags of 16x16, BK=64 (2 MFMA K-substeps).
// NPA/NPB in {1,2}: number of split parts per operand; passes: hh [+hl] [+lh].
// EPI: 0 = fp32 C0[b*strC + r*ldc + c]
//      1 = split bf16 C0/C1 [r*ldc + c]             (q,k projections)
//      2 = transposed split bf16 vT[b][c][t], b=r>>11 (v projection)
// TRI: grid.x = lower-triangular tile list (S GEMM).  KLIM: kEnd=(ti+1)*128 (PV).
template <int EPI, int NPA, int NPB, bool TRI, bool KLIM>
__global__ __launch_bounds__(256, 2) void gemm128(
    const unsigned short* __restrict__ Ahi, const unsigned short* __restrict__ Alo,
    int lda, long long strA,
    const unsigned short* __restrict__ Bhi, const unsigned short* __restrict__ Blo,
    int ldb, long long strB,
    void* __restrict__ C0, void* __restrict__ C1, int ldc, long long strC,
    int K, int ntc) {
  constexpr int TILE = 128 * 64;
  __shared__ __align__(16) unsigned short lds[(NPA + NPB) * TILE];
  unsigned short* LAhi = lds;
  unsigned short* LAlo = lds + TILE;              // valid iff NPA==2
  unsigned short* LBhi = lds + NPA * TILE;
  unsigned short* LBlo = lds + (NPA + 1) * TILE;  // valid iff NPB==2

  const int bx = blockIdx.x;
  const int b = blockIdx.y;
  int ti, tj;
  if constexpr (TRI) {  // linear idx -> (ti, tj), tj<=ti
    int rem = bx, i = 0;
    while (rem > i) { rem -= (i + 1); ++i; }
    ti = i; tj = rem;
  } else {
    ti = bx / ntc; tj = bx - ti * ntc;
  }
  const int row0 = ti << 7, col0 = tj << 7;

  const unsigned short* pAhi = Ahi + (long long)b * strA + (long long)row0 * lda;
  const unsigned short* pAlo = (NPA == 2) ? Alo + (long long)b * strA + (long long)row0 * lda : Ahi;
  const unsigned short* pBhi = Bhi + (long long)b * strB + (long long)col0 * ldb;
  const unsigned short* pBlo = (NPB == 2) ? Blo + (long long)b * strB + (long long)col0 * ldb : Bhi;

  const int kEnd = KLIM ? ((ti + 1) << 7) : K;
  const int nkt = kEnd >> 6;

  const int t = threadIdx.x;
  const int lane = t & 63, w = t >> 6;
  const int wr = (w >> 1) << 6, wc = (w & 1) << 6;
  const int fr = lane & 15, fg = lane >> 4;

  f32x4 acc[4][4];
#pragma unroll
  for (int m = 0; m < 4; ++m)
#pragma unroll
    for (int n = 0; n < 4; ++n) acc[m][n] = (f32x4){0.f, 0.f, 0.f, 0.f};

  for (int kt = 0; kt < nkt; ++kt) {
    const int k0 = kt << 6;
    // ---- stage: each thread 4 chunks of 16 B per tile; LDS linear [128][64] ----
#pragma unroll
    for (int c = 0; c < 4; ++c) {
      const int lin = c * 256 + t;
      const int r = lin >> 3, cb = (lin & 7) << 3;
      const long long go = (long long)r * lda + k0 + cb;
      gload_lds16(pAhi + go, LAhi + lin * 8);
      if constexpr (NPA == 2) gload_lds16(pAlo + go, LAlo + lin * 8);
      const long long gob = (long long)r * ldb + k0 + cb;
      gload_lds16(pBhi + gob, LBhi + lin * 8);
      if constexpr (NPB == 2) gload_lds16(pBlo + gob, LBlo + lin * 8);
    }
    __syncthreads();  // compiler emits vmcnt(0) drain before barrier -> LDS ready
#pragma unroll
    for (int ks = 0; ks < 2; ++ks) {
      short8 a0[4], a1[4];
#pragma unroll
      for (int m = 0; m < 4; ++m) {
        const int off = (wr + m * 16 + fr) * 64 + ks * 32 + fg * 8;
        a0[m] = *(const short8*)(LAhi + off);
        if constexpr (NPA == 2) a1[m] = *(const short8*)(LAlo + off);
      }
#pragma unroll
      for (int n = 0; n < 4; ++n) {
        const int off = (wc + n * 16 + fr) * 64 + ks * 32 + fg * 8;
        const short8 b0 = *(const short8*)(LBhi + off);
        short8 b1 = b0;
        if constexpr (NPB == 2) b1 = *(const short8*)(LBlo + off);
#pragma unroll
        for (int m = 0; m < 4; ++m) {
          acc[m][n] = __builtin_amdgcn_mfma_f32_16x16x32_bf16(a0[m], b0, acc[m][n], 0, 0, 0);
          if constexpr (NPB == 2)
            acc[m][n] = __builtin_amdgcn_mfma_f32_16x16x32_bf16(a0[m], b1, acc[m][n], 0, 0, 0);
          if constexpr (NPA == 2)
            acc[m][n] = __builtin_amdgcn_mfma_f32_16x16x32_bf16(a1[m], b0, acc[m][n], 0, 0, 0);
        }
      }
    }
    __syncthreads();  // protect LDS before next stage
  }

  // ---- epilogue: D layout col=lane&15, row=(lane>>4)*4+j [m89-verified] ----
#pragma unroll
  for (int m = 0; m < 4; ++m)
#pragma unroll
    for (int n = 0; n < 4; ++n)
#pragma unroll
      for (int j = 0; j < 4; ++j) {
        const int r = row0 + wr + m * 16 + fg * 4 + j;
        const int cidx = col0 + wc + n * 16 + fr;
        const float v = acc[m][n][j];
        if constexpr (EPI == 0) {
          ((float*)C0)[(long long)b * strC + (long long)r * ldc + cidx] = v;
        } else if constexpr (EPI == 1) {
          const unsigned short h = f2bf(v);
          ((unsigned short*)C0)[(long long)r * ldc + cidx] = h;
          ((unsigned short*)C1)[(long long)r * ldc + cidx] = f2bf(v - bf2f(h));
        } else {  // EPI==2: vT[b][d][t], r=(b,t) over 8192 rows, cidx=d
          const int bb = r >> 11, tt = r & 2047;
          const long long addr = (long long)bb * (1024LL * 2048) + (long long)cidx * 2048 + tt;
          const unsigned short h = f2bf(v);
          ((unsigned short*)C0)[addr] = h;
          ((unsigned short*)C1)[addr] = f2bf(v - bf2f(h));
        }
      }
}

// ---------------- causal row softmax: S fp32 -> P bf16 (zero-filled) ----------
__global__ __launch_bounds__(256) void softmax_causal_kernel(
    const float* __restrict__ S, unsigned short* __restrict__ P) {
  __shared__ float red[8];
  const int tq = blockIdx.x;  // row 0..2047
  const int b = blockIdx.y;
  const float* s = S + (long long)b * 2048 * 2048 + (long long)tq * 2048;
  unsigned short* p = P + (long long)b * 2048 * 2048 + (long long)tq * 2048;
  const int n = tq + 1;  // valid cols (cols > tq are poison: never read)
  const int t = threadIdx.x;

  float vals[8];
  float mx = -1e30f;
#pragma unroll
  for (int c = 0; c < 8; ++c) {
    const int i = t + c * 256;
    if (i < n) { vals[c] = s[i]; mx = fmaxf(mx, vals[c]); }
  }
#pragma unroll
  for (int o = 32; o > 0; o >>= 1) mx = fmaxf(mx, __shfl_xor(mx, o, 64));
  if ((t & 63) == 0) red[t >> 6] = mx;
  __syncthreads();
  mx = fmaxf(fmaxf(red[0], red[1]), fmaxf(red[2], red[3]));

  float sum = 0.f;
#pragma unroll
  for (int c = 0; c < 8; ++c) {
    const int i = t + c * 256;
    if (i < n) { const float e = __expf(vals[c] - mx); vals[c] = e; sum += e; }
  }
#pragma unroll
  for (int o = 32; o > 0; o >>= 1) sum += __shfl_xor(sum, o, 64);
  if ((t & 63) == 0) red[4 + (t >> 6)] = sum;
  __syncthreads();
  sum = (red[4] + red[5]) + (red[6] + red[7]);
  const float inv = 1.0f / sum;
#pragma unroll
  for (int c = 0; c < 8; ++c) {
    const int i = t + c * 256;
    if (i < n) p[i] = f2bf(vals[c] * inv);
  }
  for (int i = n + ((t + (2048 - n) % 256) % 256 == t ? 0 : 0), ii = t; ii < 2048; ii += 256)
    if (ii >= n) p[ii] = 0;  // zero-fill masked cols so PV can read full K rows
}

// -------------------------------- launch --------------------------------------
extern "C" void kernel_launch(void* const* d_in, const int* in_sizes, int n_in,
                              void* d_out, int out_size, void* d_ws, size_t ws_size,
                              hipStream_t stream) {
  (void)in_sizes; (void)n_in; (void)out_size; (void)ws_size;
  const float* x  = (const float*)d_in[0];
  const float* Wk = (const float*)d_in[1];  // NOTE input order: x, Wk, Wq, Wv
  const float* Wq = (const float*)d_in[2];
  const float* Wv = (const float*)d_in[3];
  char* ws = (char*)d_ws;

  float*          Sbuf = (float*)ws;                              // 64 MiB
  unsigned short* wkhi = (unsigned short*)(ws + 0);
  unsigned short* wklo = (unsigned short*)(ws + 2097152);
  unsigned short* wqhi = (unsigned short*)(ws + 4194304);
  unsigned short* wqlo = (unsigned short*)(ws + 6291456);
  unsigned short* wvhi = (unsigned short*)(ws + 8388608);
  unsigned short* wvlo = (unsigned short*)(ws + 10485760);
  unsigned short* xhi  = (unsigned short*)(ws + 12582912);
  unsigned short* xlo  = (unsigned short*)(ws + 29360128);
  unsigned short* qhi  = (unsigned short*)(ws + 67108864);
  unsigned short* qlo  = (unsigned short*)(ws + 83886080);
  unsigned short* khi  = (unsigned short*)(ws + 100663296);
  unsigned short* klo  = (unsigned short*)(ws + 117440512);
  unsigned short* Pbuf = (unsigned short*)(ws + 67108864);        // overlays q
  unsigned short* vthi = (unsigned short*)(ws + 134217728);
  unsigned short* vtlo = (unsigned short*)(ws + 150994944);

  // 1) split conversions
  split_f32_kernel<<<4096, 256, 0, stream>>>(x, xhi, xlo, 1048576);
  split_f32_kernel<<<512, 256, 0, stream>>>(Wq, wqhi, wqlo, 131072);
  split_f32_kernel<<<512, 256, 0, stream>>>(Wk, wkhi, wklo, 131072);
  split_f32_kernel<<<512, 256, 0, stream>>>(Wv, wvhi, wvlo, 131072);

  // 2) projections: M=8192, N=1024, K=1024 (grid 64x8)
  gemm128<1, 2, 2, false, false><<<dim3(512, 1), 256, 0, stream>>>(
      xhi, xlo, 1024, 0, wqhi, wqlo, 1024, 0, qhi, qlo, 1024, 0, 1024, 8);
  gemm128<1, 2, 2, false, false><<<dim3(512, 1), 256, 0, stream>>>(
      xhi, xlo, 1024, 0, wkhi, wklo, 1024, 0, khi, klo, 1024, 0, 1024, 8);
  gemm128<2, 2, 2, false, false><<<dim3(512, 1), 256, 0, stream>>>(
      xhi, xlo, 1024, 0, wvhi, wvlo, 1024, 0, vthi, vtlo, 0, 0, 1024, 8);

  // 3) S = q k^T, causal triangular tile grid (136 tiles x 4 batches)
  gemm128<0, 2, 2, true, false><<<dim3(136, 4), 256, 0, stream>>>(
      qhi, qlo, 1024, 2048LL * 1024, khi, klo, 1024, 2048LL * 1024,
      Sbuf, nullptr, 2048, 2048LL * 2048, 1024, 8);

  // 4) causal softmax -> P (bf16, zero-filled above diagonal)
  softmax_causal_kernel<<<dim3(2048, 4), 256, 0, stream>>>(Sbuf, Pbuf);

  // 5) out = P vT^T: M=2048, N=1024, K limited to (ti+1)*128 (grid 16x8 x 4)
  gemm128<0, 1, 2, false, true><<<dim3(128, 4), 256, 0, stream>>>(
      Pbuf, nullptr, 2048, 2048LL * 2048, vthi, vtlo, 2048, 1024LL * 2048,
      d_out, nullptr, 1024, 2048LL * 1024, 2048, 8);
}

// Round 2
// 378.715 us; speedup vs baseline: 1.1535x; 1.1535x over previous
//
#include <hip/hip_runtime.h>

// Causal attention head: B=4, T=2048, C=1024, fp32 in/out.
//   k = x@Wk^T, q = x@Wq^T, v = x@Wv^T ; S = q@k^T (no scale, causal) ;
//   P = softmax(S) ; out = P@v
//
// R2 changes vs R1 (counter-driven):
//  - T2 LDS XOR-swizzle (chunk ^= row&7, 16B granularity) applied via
//    pre-swizzled GLOBAL source (global_load_lds writes linearly; rule #21)
//    + same XOR on ds_read side. Kills the 16-way bank conflict
//    (SQ_LDS_BANK_CONFLICT 1.34e7 -> ~0 predicted).
//  - T1 XCD-chunked blockIdx.x swizzle on all GEMM grids (all %8==0):
//    contiguous row-tile chunks per XCD -> x fetched ~once chip-wide
//    (FETCH_SIZE 209MB -> ~90MB predicted).
//
// Workspace layout (byte offsets; lifetime overlays; total 160 MiB):
//   [0,        67108864)  S fp32 [4][2048][2048]   (written AFTER W+x are dead)
//     [0,      12582912)   W splits: wkhi,wklo,wqhi,wqlo,wvhi,wvlo (2 MiB each)
//     [12582912,46137344)  xhi, xlo (16 MiB each)
//   [67108864, 134217728) qhi,qlo,khi,klo (16 MiB each)
//     [67108864,100663296) P bf16 [4][2048][2048]  (overlays q after S-GEMM done)
//   [134217728,167772160) vthi, vtlo  [4][1024][2048] (16 MiB each)

#define GLOBAL_AS __attribute__((address_space(1)))
#define LDS_AS    __attribute__((address_space(3)))

typedef __attribute__((ext_vector_type(8))) short short8;
typedef __attribute__((ext_vector_type(4))) float f32x4;

__device__ __forceinline__ unsigned short f2bf(float f) {
  unsigned u = __float_as_uint(f);
  u += 0x7FFFu + ((u >> 16) & 1u);   // RTNE (finite values only here)
  return (unsigned short)(u >> 16);
}
__device__ __forceinline__ float bf2f(unsigned short s) {
  return __uint_as_float((unsigned)s << 16);
}

__device__ __forceinline__ void gload_lds16(const unsigned short* g, unsigned short* l) {
  __builtin_amdgcn_global_load_lds((const GLOBAL_AS unsigned int*)g,
                                   (LDS_AS unsigned int*)l, 16, 0, 0);
}

// ---------------- fp32 -> (bf16 hi, bf16 lo) split conversion -----------------
__global__ __launch_bounds__(256) void split_f32_kernel(
    const float* __restrict__ src, unsigned short* __restrict__ hi,
    unsigned short* __restrict__ lo, int n8) {
  int i = blockIdx.x * 256 + threadIdx.x;
  if (i >= n8) return;
  const float4* s4 = (const float4*)src;
  float4 a = s4[2 * i], c = s4[2 * i + 1];
  float v[8] = {a.x, a.y, a.z, a.w, c.x, c.y, c.z, c.w};
  unsigned hw[4], lw[4];
#pragma unroll
  for (int j = 0; j < 4; ++j) {
    unsigned short h0 = f2bf(v[2 * j]),     h1 = f2bf(v[2 * j + 1]);
    unsigned short l0 = f2bf(v[2 * j] - bf2f(h0));
    unsigned short l1 = f2bf(v[2 * j + 1] - bf2f(h1));
    hw[j] = (unsigned)h0 | ((unsigned)h1 << 16);
    lw[j] = (unsigned)l0 | ((unsigned)l1 << 16);
  }
  *(uint4*)(hi + 8 * i) = make_uint4(hw[0], hw[1], hw[2], hw[3]);
  *(uint4*)(lo + 8 * i) = make_uint4(lw[0], lw[1], lw[2], lw[3]);
}

// ---------------- generic 128x128-tile A·B^T GEMM, split-bf16 capable ----------
// A[M][K] (lda=K-stride), B[N][K] (ldb) — both K-contiguous. 256 thr = 4 waves,
// wave tile 64x64 = 4x4 frags of 16x16, BK=64 (2 MFMA K-substeps).
// NPA/NPB in {1,2}: number of split parts per operand; passes: hh [+hl] [+lh].
// EPI: 0 = fp32 C0[b*strC + r*ldc + c]
//      1 = split bf16 C0/C1 [r*ldc + c]             (q,k projections)
//      2 = transposed split bf16 vT[b][c][t], b=r>>11 (v projection)
// TRI: grid.x = lower-triangular tile list (S GEMM).  KLIM: kEnd=(ti+1)*128 (PV).
//
// LDS layout: linear [128][64] bf16 per tile BUT the DATA is stored swizzled:
// 16B chunk j of row r lives at linear slot (r, j^(r&7)). Achieved by
// permuting the global source chunk index in the stage loop (LDS dest stays
// linear per global_load_lds semantics), and XOR-ing on every ds_read.
template <int EPI, int NPA, int NPB, bool TRI, bool KLIM>
__global__ __launch_bounds__(256, 2) void gemm128(
    const unsigned short* __restrict__ Ahi, const unsigned short* __restrict__ Alo,
    int lda, long long strA,
    const unsigned short* __restrict__ Bhi, const unsigned short* __restrict__ Blo,
    int ldb, long long strB,
    void* __restrict__ C0, void* __restrict__ C1, int ldc, long long strC,
    int K, int ntc) {
  constexpr int TILE = 128 * 64;
  __shared__ __align__(16) unsigned short lds[(NPA + NPB) * TILE];
  unsigned short* LAhi = lds;
  unsigned short* LAlo = lds + TILE;              // valid iff NPA==2
  unsigned short* LBhi = lds + NPA * TILE;
  unsigned short* LBlo = lds + (NPA + 1) * TILE;  // valid iff NPB==2

  // T1: XCD-chunked swizzle (grid.x % 8 == 0 for all our launches)
  const int bx0 = blockIdx.x;
  const int bx = ((gridDim.x & 7) == 0) ? ((bx0 & 7) * (gridDim.x >> 3) + (bx0 >> 3)) : bx0;
  const int b = blockIdx.y;
  int ti, tj;
  if constexpr (TRI) {  // linear idx -> (ti, tj), tj<=ti
    int rem = bx, i = 0;
    while (rem > i) { rem -= (i + 1); ++i; }
    ti = i; tj = rem;
  } else {
    ti = bx / ntc; tj = bx - ti * ntc;
  }
  const int row0 = ti << 7, col0 = tj << 7;

  const unsigned short* pAhi = Ahi + (long long)b * strA + (long long)row0 * lda;
  const unsigned short* pAlo = (NPA == 2) ? Alo + (long long)b * strA + (long long)row0 * lda : Ahi;
  const unsigned short* pBhi = Bhi + (long long)b * strB + (long long)col0 * ldb;
  const unsigned short* pBlo = (NPB == 2) ? Blo + (long long)b * strB + (long long)col0 * ldb : Bhi;

  const int kEnd = KLIM ? ((ti + 1) << 7) : K;
  const int nkt = kEnd >> 6;

  const int t = threadIdx.x;
  const int lane = t & 63, w = t >> 6;
  const int wr = (w >> 1) << 6, wc = (w & 1) << 6;
  const int fr = lane & 15, fg = lane >> 4;

  f32x4 acc[4][4];
#pragma unroll
  for (int m = 0; m < 4; ++m)
#pragma unroll
    for (int n = 0; n < 4; ++n) acc[m][n] = (f32x4){0.f, 0.f, 0.f, 0.f};

  for (int kt = 0; kt < nkt; ++kt) {
    const int k0 = kt << 6;
    // ---- stage: 4 chunks of 16 B per thread per tile; LDS dest linear,
    //      global source chunk-index XOR-swizzled (j ^ (row&7)) ----
#pragma unroll
    for (int c = 0; c < 4; ++c) {
      const int lin = c * 256 + t;
      const int r = lin >> 3;
      const int js = (lin & 7) ^ (r & 7);      // swizzled source chunk
      const long long go = (long long)r * lda + k0 + js * 8;
      gload_lds16(pAhi + go, LAhi + lin * 8);
      if constexpr (NPA == 2) gload_lds16(pAlo + go, LAlo + lin * 8);
      const long long gob = (long long)r * ldb + k0 + js * 8;
      gload_lds16(pBhi + gob, LBhi + lin * 8);
      if constexpr (NPB == 2) gload_lds16(pBlo + gob, LBlo + lin * 8);
    }
    __syncthreads();  // compiler emits vmcnt(0) drain before barrier -> LDS ready
#pragma unroll
    for (int ks = 0; ks < 2; ++ks) {
      short8 a0[4], a1[4];
#pragma unroll
      for (int m = 0; m < 4; ++m) {
        const int row = wr + m * 16 + fr;
        const int cj = (ks * 4 + fg) ^ (row & 7);   // de-swizzle on read
        const int off = row * 64 + cj * 8;
        a0[m] = *(const short8*)(LAhi + off);
        if constexpr (NPA == 2) a1[m] = *(const short8*)(LAlo + off);
      }
#pragma unroll
      for (int n = 0; n < 4; ++n) {
        const int row = wc + n * 16 + fr;
        const int cj = (ks * 4 + fg) ^ (row & 7);
        const int off = row * 64 + cj * 8;
        const short8 b0 = *(const short8*)(LBhi + off);
        short8 b1 = b0;
        if constexpr (NPB == 2) b1 = *(const short8*)(LBlo + off);
#pragma unroll
        for (int m = 0; m < 4; ++m) {
          acc[m][n] = __builtin_amdgcn_mfma_f32_16x16x32_bf16(a0[m], b0, acc[m][n], 0, 0, 0);
          if constexpr (NPB == 2)
            acc[m][n] = __builtin_amdgcn_mfma_f32_16x16x32_bf16(a0[m], b1, acc[m][n], 0, 0, 0);
          if constexpr (NPA == 2)
            acc[m][n] = __builtin_amdgcn_mfma_f32_16x16x32_bf16(a1[m], b0, acc[m][n], 0, 0, 0);
        }
      }
    }
    __syncthreads();  // protect LDS before next stage
  }

  // ---- epilogue: D layout col=lane&15, row=(lane>>4)*4+j [m89-verified] ----
#pragma unroll
  for (int m = 0; m < 4; ++m)
#pragma unroll
    for (int n = 0; n < 4; ++n)
#pragma unroll
      for (int j = 0; j < 4; ++j) {
        const int r = row0 + wr + m * 16 + fg * 4 + j;
        const int cidx = col0 + wc + n * 16 + fr;
        const float v = acc[m][n][j];
        if constexpr (EPI == 0) {
          ((float*)C0)[(long long)b * strC + (long long)r * ldc + cidx] = v;
        } else if constexpr (EPI == 1) {
          const unsigned short h = f2bf(v);
          ((unsigned short*)C0)[(long long)r * ldc + cidx] = h;
          ((unsigned short*)C1)[(long long)r * ldc + cidx] = f2bf(v - bf2f(h));
        } else {  // EPI==2: vT[b][d][t], r=(b,t) over 8192 rows, cidx=d
          const int bb = r >> 11, tt = r & 2047;
          const long long addr = (long long)bb * (1024LL * 2048) + (long long)cidx * 2048 + tt;
          const unsigned short h = f2bf(v);
          ((unsigned short*)C0)[addr] = h;
          ((unsigned short*)C1)[addr] = f2bf(v - bf2f(h));
        }
      }
}

// ---------------- causal row softmax: S fp32 -> P bf16 (zero-filled) ----------
__global__ __launch_bounds__(256) void softmax_causal_kernel(
    const float* __restrict__ S, unsigned short* __restrict__ P) {
  __shared__ float red[8];
  const int tq = blockIdx.x;  // row 0..2047
  const int b = blockIdx.y;
  const float* s = S + (long long)b * 2048 * 2048 + (long long)tq * 2048;
  unsigned short* p = P + (long long)b * 2048 * 2048 + (long long)tq * 2048;
  const int n = tq + 1;  // valid cols (cols > tq are poison: never read)
  const int t = threadIdx.x;

  float vals[8];
  float mx = -1e30f;
#pragma unroll
  for (int c = 0; c < 8; ++c) {
    const int i = t + c * 256;
    if (i < n) { vals[c] = s[i]; mx = fmaxf(mx, vals[c]); }
  }
#pragma unroll
  for (int o = 32; o > 0; o >>= 1) mx = fmaxf(mx, __shfl_xor(mx, o, 64));
  if ((t & 63) == 0) red[t >> 6] = mx;
  __syncthreads();
  mx = fmaxf(fmaxf(red[0], red[1]), fmaxf(red[2], red[3]));

  float sum = 0.f;
#pragma unroll
  for (int c = 0; c < 8; ++c) {
    const int i = t + c * 256;
    if (i < n) { const float e = __expf(vals[c] - mx); vals[c] = e; sum += e; }
  }
#pragma unroll
  for (int o = 32; o > 0; o >>= 1) sum += __shfl_xor(sum, o, 64);
  if ((t & 63) == 0) red[4 + (t >> 6)] = sum;
  __syncthreads();
  sum = (red[4] + red[5]) + (red[6] + red[7]);
  const float inv = 1.0f / sum;
#pragma unroll
  for (int c = 0; c < 8; ++c) {
    const int i = t + c * 256;
    if (i < n) p[i] = f2bf(vals[c] * inv);
  }
  for (int ii = t; ii < 2048; ii += 256)
    if (ii >= n) p[ii] = 0;  // zero-fill masked cols so PV can read full K rows
}

// -------------------------------- launch --------------------------------------
extern "C" void kernel_launch(void* const* d_in, const int* in_sizes, int n_in,
                              void* d_out, int out_size, void* d_ws, size_t ws_size,
                              hipStream_t stream) {
  (void)in_sizes; (void)n_in; (void)out_size; (void)ws_size;
  const float* x  = (const float*)d_in[0];
  const float* Wk = (const float*)d_in[1];  // NOTE input order: x, Wk, Wq, Wv
  const float* Wq = (const float*)d_in[2];
  const float* Wv = (const float*)d_in[3];
  char* ws = (char*)d_ws;

  float*          Sbuf = (float*)ws;                              // 64 MiB
  unsigned short* wkhi = (unsigned short*)(ws + 0);
  unsigned short* wklo = (unsigned short*)(ws + 2097152);
  unsigned short* wqhi = (unsigned short*)(ws + 4194304);
  unsigned short* wqlo = (unsigned short*)(ws + 6291456);
  unsigned short* wvhi = (unsigned short*)(ws + 8388608);
  unsigned short* wvlo = (unsigned short*)(ws + 10485760);
  unsigned short* xhi  = (unsigned short*)(ws + 12582912);
  unsigned short* xlo  = (unsigned short*)(ws + 29360128);
  unsigned short* qhi  = (unsigned short*)(ws + 67108864);
  unsigned short* qlo  = (unsigned short*)(ws + 83886080);
  unsigned short* khi  = (unsigned short*)(ws + 100663296);
  unsigned short* klo  = (unsigned short*)(ws + 117440512);
  unsigned short* Pbuf = (unsigned short*)(ws + 67108864);        // overlays q
  unsigned short* vthi = (unsigned short*)(ws + 134217728);
  unsigned short* vtlo = (unsigned short*)(ws + 150994944);

  // 1) split conversions
  split_f32_kernel<<<4096, 256, 0, stream>>>(x, xhi, xlo, 1048576);
  split_f32_kernel<<<512, 256, 0, stream>>>(Wq, wqhi, wqlo, 131072);
  split_f32_kernel<<<512, 256, 0, stream>>>(Wk, wkhi, wklo, 131072);
  split_f32_kernel<<<512, 256, 0, stream>>>(Wv, wvhi, wvlo, 131072);

  // 2) projections: M=8192, N=1024, K=1024 (grid 64x8 -> 512, %8==0)
  gemm128<1, 2, 2, false, false><<<dim3(512, 1), 256, 0, stream>>>(
      xhi, xlo, 1024, 0, wqhi, wqlo, 1024, 0, qhi, qlo, 1024, 0, 1024, 8);
  gemm128<1, 2, 2, false, false><<<dim3(512, 1), 256, 0, stream>>>(
      xhi, xlo, 1024, 0, wkhi, wklo, 1024, 0, khi, klo, 1024, 0, 1024, 8);
  gemm128<2, 2, 2, false, false><<<dim3(512, 1), 256, 0, stream>>>(
      xhi, xlo, 1024, 0, wvhi, wvlo, 1024, 0, vthi, vtlo, 0, 0, 1024, 8);

  // 3) S = q k^T, causal triangular tile grid (136 tiles x 4 batches, %8==0)
  gemm128<0, 2, 2, true, false><<<dim3(136, 4), 256, 0, stream>>>(
      qhi, qlo, 1024, 2048LL * 1024, khi, klo, 1024, 2048LL * 1024,
      Sbuf, nullptr, 2048, 2048LL * 2048, 1024, 8);

  // 4) causal softmax -> P (bf16, zero-filled above diagonal)
  softmax_causal_kernel<<<dim3(2048, 4), 256, 0, stream>>>(Sbuf, Pbuf);

  // 5) out = P vT^T: M=2048, N=1024, K limited to (ti+1)*128 (grid 128, %8==0)
  gemm128<0, 1, 2, false, true><<<dim3(128, 4), 256, 0, stream>>>(
      Pbuf, nullptr, 2048, 2048LL * 2048, vthi, vtlo, 2048, 1024LL * 2048,
      d_out, nullptr, 1024, 2048LL * 1024, 2048, 8);
}